// Round 9
// baseline (806.127 us; speedup 1.0000x reference)
//
#include <hip/hip_runtime.h>
#include <stdint.h>

#define B_ 64
#define T_ 256
#define K_ 48
#define KK 2304
#define START_TAG 46
#define END_TAG 47
#define LOG2E 1.4426950408889634f
#define LN2   0.6931471805599453f
#define ESHIFT 6.0f
#define NEGBIG -1.0e9f
#define POSBIG  1.0e9f
#define NRING 6

typedef const __attribute__((address_space(1))) void* gas_t;
typedef __attribute__((address_space(3))) void* las_t;
typedef __attribute__((ext_vector_type(4))) float f32x4;
typedef __attribute__((ext_vector_type(4))) short s16x4;

#define EXP2F(x) __builtin_amdgcn_exp2f(x)
#define LOG2F(x) __builtin_amdgcn_logf(x)
#define EX(v) EXP2F(fmaf((v), LOG2E, -ESHIFT))
#define MFMA16(a, b, c) __builtin_amdgcn_mfma_f32_16x16x16bf16_1k((a), (b), (c), 0, 0, 0)

static __device__ __forceinline__ int cvtpk(float lo, float hi) {
    int r; asm("v_cvt_pk_bf16_f32 %0, %1, %2" : "=v"(r) : "v"(lo), "v"(hi)); return r;
}
static __device__ __forceinline__ s16x4 pack2(int lo, int hi) {
    union { int i[2]; s16x4 s; } u; u.i[0] = lo; u.i[1] = hi; return u.s;
}
static __device__ __forceinline__ void issue_tile(const float* src, float* slot, int lane) {
#pragma unroll
    for (int q = 0; q < 9; ++q)
        __builtin_amdgcn_global_load_lds((gas_t)(src + q * 256 + lane * 4),
                                         (las_t)(slot + q * 256), 16, 0, 0);
}

// grid 256 = 64 b x 4 segments; ONE wave per block.
// acc = (E_0 ... E_{n-1})^T built via D = E_i^T x B, B carries the product (bf16).
// NO dummy DMA: main loop (constant vmcnt(36)) + peeled drained tail (vmcnt(0)).
__launch_bounds__(64, 1)
__global__ void seg_kernel(const float* __restrict__ scores,
                           const int* __restrict__ lengths,
                           float* __restrict__ wsW,
                           int* __restrict__ flags) {
    __shared__ __align__(16) float ring[NRING][KK];   // 55296 B

    const int bid  = blockIdx.x;
    const int b    = bid >> 2;
    const int seg  = bid & 3;
    const int lane = threadIdx.x;

    int len = lengths[b]; len = min(max(len, 1), T_);
    const int last_t  = len - 1;
    const int segbase = seg * 64;
    const int cap     = (seg == 3) ? 63 : 64;
    const int n       = min(max(last_t - segbase, 0), cap);

    float* Wp = wsW + (size_t)bid * KK;

    if (n == 0) {   // identity transfer in log2 domain
        for (int e = lane; e < KK; e += 64) {
            int m = e / K_, c = e - m * K_;
            Wp[e] = (m == c) ? 0.f : NEGBIG;
        }
        if (lane == 0) flags[bid] = 0;
        return;
    }

    const float* sb = scores + (size_t)b * T_ * KK;
    const float* tb = sb + (size_t)(segbase + 1) * KK;   // tile k <-> t = segbase+1+k

    // ---- prologue: issue REAL tiles only, k = 0..min(5,n)-1 ----
    const int npre = (n < 5) ? n : 5;
    for (int k = 0; k < npre; ++k)
        issue_tile(tb + (size_t)k * KK, ring[k], lane);

    // ---- identity B fragments (B[k][col] = 1 iff k == col) ----
    const int col = lane & 15, L = lane >> 4;
    s16x4 aFr[9], bFr[9];
    f32x4 acc[9];
    const f32x4 zf = (f32x4){0.f, 0.f, 0.f, 0.f};
    {
        const int sel = ((col >> 2) == L) ? (col & 3) : -1;
        const int lo = (sel == 0) ? 0x3F80 : ((sel == 1) ? 0x3F800000 : 0);
        const int hi = (sel == 2) ? 0x3F80 : ((sel == 3) ? 0x3F800000 : 0);
#pragma unroll
        for (int o = 0; o < 9; ++o) { bFr[o] = pack2(0, 0); acc[o] = zf; }
        bFr[0] = pack2(lo, hi); bFr[4] = pack2(lo, hi); bFr[8] = pack2(lo, hi);
    }

    const int k0 = 4 * L;   // A k-base; A[m][k] = E[k][m] = ring[k*48 + m]
    const int M  = (n > 5) ? (n - 5) : 0;   // main iters (always have 5 tiles in flight)

    for (int i = 0; i < n; ++i) {
        if (i < M) { asm volatile("s_waitcnt vmcnt(36)" ::: "memory"); }
        else       { asm volatile("s_waitcnt vmcnt(0)"  ::: "memory"); }
        const float* rs = ring[i % NRING];

        // A fragments straight from ring: element j = A[16rt+col][16kc+k0+j]
#pragma unroll
        for (int kc = 0; kc < 3; ++kc)
#pragma unroll
            for (int rt = 0; rt < 3; ++rt) {
                const float* p = rs + (16 * kc + k0) * K_ + (col + 16 * rt);
                const float e0 = EX(p[0 * K_]);
                const float e1 = EX(p[1 * K_]);
                const float e2 = EX(p[2 * K_]);
                const float e3 = EX(p[3 * K_]);
                aFr[kc * 3 + rt] = pack2(cvtpk(e0, e1), cvtpk(e2, e3));
            }

        asm volatile("s_waitcnt lgkmcnt(0)" ::: "memory");  // ring reads retired
        if (i < M)   // issue REAL tile i+5 into slot (i+5)%6 (= (i-1)%6, consumed)
            issue_tile(tb + (size_t)(i + 5) * KK, ring[(i + 5) % NRING], lane);

        // D = A x B
#pragma unroll
        for (int rt = 0; rt < 3; ++rt)
#pragma unroll
            for (int ct = 0; ct < 3; ++ct)
                acc[rt * 3 + ct] = MFMA16(aFr[rt], bFr[ct], zf);            // kc = 0
#pragma unroll
        for (int kc = 1; kc < 3; ++kc)
#pragma unroll
            for (int rt = 0; rt < 3; ++rt)
#pragma unroll
                for (int ct = 0; ct < 3; ++ct)
                    acc[rt * 3 + ct] =
                        MFMA16(aFr[kc * 3 + rt], bFr[kc * 3 + ct], acc[rt * 3 + ct]);

        // D rows (4L+r) -> next B k (4L+j): lane-local repack
#pragma unroll
        for (int o = 0; o < 9; ++o)
            bFr[o] = pack2(cvtpk(acc[o].x, acc[o].y), cvtpk(acc[o].z, acc[o].w));
    }

    asm volatile("s_waitcnt vmcnt(0)" ::: "memory");

    // ---- epilogue: flag + W = clamp(log2(acc)) + 6n ----
    const float sh = ESHIFT * (float)n;
    bool bad = false;
#pragma unroll
    for (int rt = 0; rt < 3; ++rt)
#pragma unroll
        for (int ct = 0; ct < 3; ++ct)
#pragma unroll
            for (int r = 0; r < 4; ++r) {
                const float x = acc[rt * 3 + ct][r];
                bad = bad || !(x > 0.f && x < 3.0e38f);   // legit acc strictly positive
                const float w = fminf(fmaxf(LOG2F(x), NEGBIG), POSBIG);
                Wp[(rt * 16 + 4 * L + r) * K_ + ct * 16 + col] = w + sh;
            }
    const bool anybad = __any(bad);
    if (lane == 0) flags[bid] = anybad ? 1 : 0;
}

// grid 64 (one per b), block 64: compose init with 4 segment matrices + gold.
// Flagged segments are recomputed exactly (scalar LSE per step, R3-proven math).
__global__ void combine_kernel(const float* __restrict__ scores,
                               const int* __restrict__ targets,
                               const int* __restrict__ lengths,
                               const float* __restrict__ wsW,
                               const int* __restrict__ flags,
                               float* __restrict__ losses) {
    __shared__ float vsh[K_];
    __shared__ __align__(16) float tile[KK];
    const int b = blockIdx.x;
    const int j = threadIdx.x;
    int len = lengths[b]; len = min(max(len, 1), T_);
    const int last_t = len - 1;
    const float* sb = scores + (size_t)b * T_ * KK;

    float g = 0.f;
#pragma unroll
    for (int r = 0; r < 4; ++r) {
        int t = j + 64 * r;
        if (t < len) g += sb[(size_t)t * KK + targets[b * T_ + t]];
    }
#pragma unroll
    for (int off = 1; off < 64; off <<= 1) g += __shfl_xor(g, off);

    float v = (j < K_) ? sb[START_TAG * K_ + j] * LOG2E : 0.f;   // log2 units

#pragma unroll 1
    for (int s = 0; s < 4; ++s) {
        const int cap = (s == 3) ? 63 : 64;
        const int ns  = min(max(last_t - 64 * s, 0), cap);
        if (ns == 0) continue;
        const int flag = flags[b * 4 + s];

        __syncthreads();
        if (j < K_) vsh[j] = v;
        __syncthreads();

        if (!flag) {
            if (j < K_) {
                const float* Wr = wsW + (size_t)(b * 4 + s) * KK + j * K_;
                float m = -3.0e38f;
                float xs[K_];
#pragma unroll
                for (int c = 0; c < K_; ++c) { xs[c] = vsh[c] + Wr[c]; m = fmaxf(m, xs[c]); }
                float ssum = 0.f;
#pragma unroll
                for (int c = 0; c < K_; ++c) ssum += EXP2F(xs[c] - m);
                v = m + LOG2F(ssum);
            }
        } else {
            // exact scalar recompute of this segment's steps
#pragma unroll 1
            for (int k = 0; k < ns; ++k) {
                const float* st = sb + (size_t)(64 * s + 1 + k) * KK;
                for (int q = j; q < KK / 4; q += 64)
                    ((float4*)tile)[q] = ((const float4*)st)[q];
                __syncthreads();
                float vn = 0.f;
                if (j < K_) {
                    float m = -3.0e38f;
#pragma unroll
                    for (int i2 = 0; i2 < K_; ++i2)
                        m = fmaxf(m, vsh[i2] + tile[i2 * K_ + j] * LOG2E);
                    float ssum = 0.f;
#pragma unroll
                    for (int i2 = 0; i2 < K_; ++i2)
                        ssum += EXP2F(vsh[i2] + tile[i2 * K_ + j] * LOG2E - m);
                    vn = m + LOG2F(ssum);
                }
                __syncthreads();
                if (j < K_) vsh[j] = vn;
                __syncthreads();
            }
            if (j < K_) v = vsh[j];
        }
    }

    float vEnd = __shfl(v, END_TAG);
    if (j == 0) losses[b] = LN2 * vEnd - g;
}

__global__ void reduce_kernel(const float* __restrict__ losses, float* __restrict__ out) {
    float v = losses[threadIdx.x];
#pragma unroll
    for (int off = 1; off < 64; off <<= 1) v += __shfl_xor(v, off);
    if (threadIdx.x == 0) out[0] = v * (1.0f / 64.0f);
}

extern "C" void kernel_launch(void* const* d_in, const int* in_sizes, int n_in,
                              void* d_out, int out_size, void* d_ws, size_t ws_size,
                              hipStream_t stream) {
    const float* scores  = (const float*)d_in[0];
    const int*   targets = (const int*)d_in[1];
    const int*   lengths = (const int*)d_in[2];
    float* wsW    = (float*)d_ws;                 // 256 * 2304 floats
    float* losses = wsW + 256 * KK;               // + 64 floats
    int*   flags  = (int*)(losses + 64);          // + 256 ints

    seg_kernel<<<dim3(256), dim3(64), 0, stream>>>(scores, lengths, wsW, flags);
    combine_kernel<<<dim3(64), dim3(64), 0, stream>>>(scores, targets, lengths, wsW, flags, losses);
    reduce_kernel<<<dim3(1), dim3(64), 0, stream>>>(losses, (float*)d_out);
}

// Round 10
// 800.512 us; speedup vs baseline: 1.0070x; 1.0070x over previous
//
#include <hip/hip_runtime.h>
#include <stdint.h>

#define B_ 64
#define T_ 256
#define K_ 48
#define KK 2304
#define START_TAG 46
#define END_TAG 47
#define LOG2E 1.4426950408889634f
#define LN2   0.6931471805599453f
#define ESHIFT 6.0f
#define NEGBIG -1.0e9f
#define POSBIG  1.0e9f

typedef __attribute__((ext_vector_type(4))) float f32x4;
typedef __attribute__((ext_vector_type(4))) short s16x4;

#define EXP2F(x) __builtin_amdgcn_exp2f(x)
#define LOG2F(x) __builtin_amdgcn_logf(x)
#define EX(v) EXP2F(fmaf((v), LOG2E, -ESHIFT))
#define MFMA16(a, b, c) __builtin_amdgcn_mfma_f32_16x16x16bf16_1k((a), (b), (c), 0, 0, 0)

static __device__ __forceinline__ int cvtpk(float lo, float hi) {
    int r; asm("v_cvt_pk_bf16_f32 %0, %1, %2" : "=v"(r) : "v"(lo), "v"(hi)); return r;
}
static __device__ __forceinline__ s16x4 pack2(int lo, int hi) {
    union { int i[2]; s16x4 s; } u; u.i[0] = lo; u.i[1] = hi; return u.s;
}

// Load tile k's A-fragment raw f32 values straight from global (all indices static).
static __device__ __forceinline__ void load_tile(float (&raw)[36], const float* tb,
                                                 int k, int L, int col) {
    const float* tg = tb + (size_t)k * KK;
#pragma unroll
    for (int kc = 0; kc < 3; ++kc)
#pragma unroll
        for (int rt = 0; rt < 3; ++rt)
#pragma unroll
            for (int j = 0; j < 4; ++j)
                raw[(kc * 3 + rt) * 4 + j] = tg[(16 * kc + 4 * L + j) * K_ + 16 * rt + col];
}

static __device__ __forceinline__ void conv_step(const float (&raw)[36], s16x4 (&aFr)[9]) {
#pragma unroll
    for (int o = 0; o < 9; ++o)
        aFr[o] = pack2(cvtpk(EX(raw[o * 4 + 0]), EX(raw[o * 4 + 1])),
                       cvtpk(EX(raw[o * 4 + 2]), EX(raw[o * 4 + 3])));
}

static __device__ __forceinline__ void mm_step(const s16x4 (&aFr)[9], s16x4 (&bFr)[9],
                                               f32x4 (&acc)[9]) {
    const f32x4 zf = (f32x4){0.f, 0.f, 0.f, 0.f};
#pragma unroll
    for (int rt = 0; rt < 3; ++rt)
#pragma unroll
        for (int ct = 0; ct < 3; ++ct)
            acc[rt * 3 + ct] = MFMA16(aFr[rt], bFr[ct], zf);                // kc = 0
#pragma unroll
    for (int kc = 1; kc < 3; ++kc)
#pragma unroll
        for (int rt = 0; rt < 3; ++rt)
#pragma unroll
            for (int ct = 0; ct < 3; ++ct)
                acc[rt * 3 + ct] =
                    MFMA16(aFr[kc * 3 + rt], bFr[kc * 3 + ct], acc[rt * 3 + ct]);
    // D rows (4L+r) -> next B k (4L+j): lane-local repack
#pragma unroll
    for (int o = 0; o < 9; ++o)
        bFr[o] = pack2(cvtpk(acc[o].x, acc[o].y), cvtpk(acc[o].z, acc[o].w));
}

// grid 256 = 64 b x 4 segments; ONE wave per block; ZERO LDS, ZERO manual waitcnt.
// acc = (E_0 ... E_{n-1})^T via D = E_i^T x B, B carries the product (bf16).
__launch_bounds__(64, 1)
__global__ void seg_kernel(const float* __restrict__ scores,
                           const int* __restrict__ lengths,
                           float* __restrict__ wsW,
                           int* __restrict__ flags) {
    const int bid  = blockIdx.x;
    const int b    = bid >> 2;
    const int seg  = bid & 3;
    const int lane = threadIdx.x;

    int len = lengths[b]; len = min(max(len, 1), T_);
    const int last_t  = len - 1;
    const int segbase = seg * 64;
    const int cap     = (seg == 3) ? 63 : 64;
    const int n       = min(max(last_t - segbase, 0), cap);

    float* Wp = wsW + (size_t)bid * KK;

    if (n == 0) {   // identity transfer in log2 domain
        for (int e = lane; e < KK; e += 64) {
            int m = e / K_, c = e - m * K_;
            Wp[e] = (m == c) ? 0.f : NEGBIG;
        }
        if (lane == 0) flags[bid] = 0;
        return;
    }

    const float* sb = scores + (size_t)b * T_ * KK;
    const float* tb = sb + (size_t)(segbase + 1) * KK;   // tile k <-> t = segbase+1+k

    const int col = lane & 15, L = lane >> 4;

    // identity B fragments (B[k][col] = 1 iff k == col)
    s16x4 aFr[9], bFr[9];
    f32x4 acc[9];
    {
        const int sel = ((col >> 2) == L) ? (col & 3) : -1;
        const int lo = (sel == 0) ? 0x3F80 : ((sel == 1) ? 0x3F800000 : 0);
        const int hi = (sel == 2) ? 0x3F80 : ((sel == 3) ? 0x3F800000 : 0);
#pragma unroll
        for (int o = 0; o < 9; ++o) bFr[o] = pack2(0, 0);
        bFr[0] = pack2(lo, hi); bFr[4] = pack2(lo, hi); bFr[8] = pack2(lo, hi);
    }

    float rawA[36], rawB[36];
    load_tile(rawA, tb, 0, L, col);
    if (n > 1) load_tile(rawB, tb, 1, L, col);

    int i = 0;
#pragma unroll 1
    while (i + 1 < n) {
        conv_step(rawA, aFr);
        if (i + 2 < n) load_tile(rawA, tb, i + 2, L, col);   // prefetch 2 ahead
        mm_step(aFr, bFr, acc);
        conv_step(rawB, aFr);
        if (i + 3 < n) load_tile(rawB, tb, i + 3, L, col);
        mm_step(aFr, bFr, acc);
        i += 2;
    }
    if (i < n) {          // n odd tail: tile n-1 (even index) lives in rawA
        conv_step(rawA, aFr);
        mm_step(aFr, bFr, acc);
    }

    // ---- epilogue: flag + W = clamp(log2(acc)) + 6n ----
    const float sh = ESHIFT * (float)n;
    bool bad = false;
#pragma unroll
    for (int rt = 0; rt < 3; ++rt)
#pragma unroll
        for (int ct = 0; ct < 3; ++ct)
#pragma unroll
            for (int r = 0; r < 4; ++r) {
                const float x = acc[rt * 3 + ct][r];
                bad = bad || !(x > 0.f && x < 3.0e38f);   // legit acc strictly positive
                const float w = fminf(fmaxf(LOG2F(x), NEGBIG), POSBIG);
                Wp[(rt * 16 + 4 * L + r) * K_ + ct * 16 + col] = w + sh;
            }
    const bool anybad = __any(bad);
    if (lane == 0) flags[bid] = anybad ? 1 : 0;
}

// grid 64 (one per b), block 64: compose init with 4 segment matrices + gold.
// Flagged segments are recomputed exactly (scalar LSE per step, proven in R9).
__global__ void combine_kernel(const float* __restrict__ scores,
                               const int* __restrict__ targets,
                               const int* __restrict__ lengths,
                               const float* __restrict__ wsW,
                               const int* __restrict__ flags,
                               float* __restrict__ losses) {
    __shared__ float vsh[K_];
    __shared__ __align__(16) float tile[KK];
    const int b = blockIdx.x;
    const int j = threadIdx.x;
    int len = lengths[b]; len = min(max(len, 1), T_);
    const int last_t = len - 1;
    const float* sb = scores + (size_t)b * T_ * KK;

    float g = 0.f;
#pragma unroll
    for (int r = 0; r < 4; ++r) {
        int t = j + 64 * r;
        if (t < len) g += sb[(size_t)t * KK + targets[b * T_ + t]];
    }
#pragma unroll
    for (int off = 1; off < 64; off <<= 1) g += __shfl_xor(g, off);

    float v = (j < K_) ? sb[START_TAG * K_ + j] * LOG2E : 0.f;   // log2 units

#pragma unroll 1
    for (int s = 0; s < 4; ++s) {
        const int cap = (s == 3) ? 63 : 64;
        const int ns  = min(max(last_t - 64 * s, 0), cap);
        if (ns == 0) continue;
        const int flag = flags[b * 4 + s];

        __syncthreads();
        if (j < K_) vsh[j] = v;
        __syncthreads();

        if (!flag) {
            if (j < K_) {
                const float* Wr = wsW + (size_t)(b * 4 + s) * KK + j * K_;
                float m = -3.0e38f;
                float xs[K_];
#pragma unroll
                for (int c = 0; c < K_; ++c) { xs[c] = vsh[c] + Wr[c]; m = fmaxf(m, xs[c]); }
                float ssum = 0.f;
#pragma unroll
                for (int c = 0; c < K_; ++c) ssum += EXP2F(xs[c] - m);
                v = m + LOG2F(ssum);
            }
        } else {
            // exact scalar recompute of this segment's steps
#pragma unroll 1
            for (int k = 0; k < ns; ++k) {
                const float* st = sb + (size_t)(64 * s + 1 + k) * KK;
                for (int q = j; q < KK / 4; q += 64)
                    ((float4*)tile)[q] = ((const float4*)st)[q];
                __syncthreads();
                float vn = 0.f;
                if (j < K_) {
                    float m = -3.0e38f;
#pragma unroll
                    for (int i2 = 0; i2 < K_; ++i2)
                        m = fmaxf(m, vsh[i2] + tile[i2 * K_ + j] * LOG2E);
                    float ssum = 0.f;
#pragma unroll
                    for (int i2 = 0; i2 < K_; ++i2)
                        ssum += EXP2F(vsh[i2] + tile[i2 * K_ + j] * LOG2E - m);
                    vn = m + LOG2F(ssum);
                }
                __syncthreads();
                if (j < K_) vsh[j] = vn;
                __syncthreads();
            }
            if (j < K_) v = vsh[j];
        }
    }

    float vEnd = __shfl(v, END_TAG);
    if (j == 0) losses[b] = LN2 * vEnd - g;
}

__global__ void reduce_kernel(const float* __restrict__ losses, float* __restrict__ out) {
    float v = losses[threadIdx.x];
#pragma unroll
    for (int off = 1; off < 64; off <<= 1) v += __shfl_xor(v, off);
    if (threadIdx.x == 0) out[0] = v * (1.0f / 64.0f);
}

extern "C" void kernel_launch(void* const* d_in, const int* in_sizes, int n_in,
                              void* d_out, int out_size, void* d_ws, size_t ws_size,
                              hipStream_t stream) {
    const float* scores  = (const float*)d_in[0];
    const int*   targets = (const int*)d_in[1];
    const int*   lengths = (const int*)d_in[2];
    float* wsW    = (float*)d_ws;                 // 256 * 2304 floats
    float* losses = wsW + 256 * KK;               // + 64 floats
    int*   flags  = (int*)(losses + 64);          // + 256 ints

    seg_kernel<<<dim3(256), dim3(64), 0, stream>>>(scores, lengths, wsW, flags);
    combine_kernel<<<dim3(64), dim3(64), 0, stream>>>(scores, targets, lengths, wsW, flags, losses);
    reduce_kernel<<<dim3(1), dim3(64), 0, stream>>>(losses, (float*)d_out);
}

// Round 11
// 795.886 us; speedup vs baseline: 1.0129x; 1.0058x over previous
//
#include <hip/hip_runtime.h>
#include <stdint.h>

#define B_ 64
#define T_ 256
#define K_ 48
#define KK 2304
#define START_TAG 46
#define END_TAG 47
#define LOG2E 1.4426950408889634f
#define LN2   0.6931471805599453f
#define ESHIFT 6.0f
#define NEGBIG -1.0e9f
#define POSBIG  1.0e9f

typedef __attribute__((ext_vector_type(4))) float f32x4;
typedef __attribute__((ext_vector_type(4))) short s16x4;

#define EXP2F(x) __builtin_amdgcn_exp2f(x)
#define LOG2F(x) __builtin_amdgcn_logf(x)
#define EX(v) EXP2F(fmaf((v), LOG2E, -ESHIFT))
#define MFMA16(a, b, c) __builtin_amdgcn_mfma_f32_16x16x16bf16_1k((a), (b), (c), 0, 0, 0)

static __device__ __forceinline__ int cvtpk(float lo, float hi) {
    int r; asm("v_cvt_pk_bf16_f32 %0, %1, %2" : "=v"(r) : "v"(lo), "v"(hi)); return r;
}
static __device__ __forceinline__ s16x4 pack2(int lo, int hi) {
    union { int i[2]; s16x4 s; } u; u.i[0] = lo; u.i[1] = hi; return u.s;
}
static __device__ __forceinline__ float bfr(float x) {   // bf16 RNE round (same path as cvtpk)
    int r = cvtpk(x, x);
    return __int_as_float((r & 0xFFFF) << 16);
}

// Load tile k's A-fragment raw f32 values straight from global (all indices static).
static __device__ __forceinline__ void load_tile(float (&raw)[36], const float* tb,
                                                 int k, int L, int col) {
    const float* tg = tb + (size_t)k * KK;
#pragma unroll
    for (int kc = 0; kc < 3; ++kc)
#pragma unroll
        for (int rt = 0; rt < 3; ++rt)
#pragma unroll
            for (int j = 0; j < 4; ++j)
                raw[(kc * 3 + rt) * 4 + j] = tg[(16 * kc + 4 * L + j) * K_ + 16 * rt + col];
}

static __device__ __forceinline__ void conv_step(const float (&raw)[36], s16x4 (&aFr)[9]) {
#pragma unroll
    for (int o = 0; o < 9; ++o)
        aFr[o] = pack2(cvtpk(EX(raw[o * 4 + 0]), EX(raw[o * 4 + 1])),
                       cvtpk(EX(raw[o * 4 + 2]), EX(raw[o * 4 + 3])));
}

static __device__ __forceinline__ void mm_step(const s16x4 (&aFr)[9], s16x4 (&bFr)[9],
                                               f32x4 (&acc)[9]) {
    const f32x4 zf = (f32x4){0.f, 0.f, 0.f, 0.f};
#pragma unroll
    for (int rt = 0; rt < 3; ++rt)
#pragma unroll
        for (int ct = 0; ct < 3; ++ct)
            acc[rt * 3 + ct] = MFMA16(aFr[rt], bFr[ct], zf);                // kc = 0
#pragma unroll
    for (int kc = 1; kc < 3; ++kc)
#pragma unroll
        for (int rt = 0; rt < 3; ++rt)
#pragma unroll
            for (int ct = 0; ct < 3; ++ct)
                acc[rt * 3 + ct] =
                    MFMA16(aFr[kc * 3 + rt], bFr[kc * 3 + ct], acc[rt * 3 + ct]);
    // D rows (4L+r) -> next B k (4L+j): lane-local repack
#pragma unroll
    for (int o = 0; o < 9; ++o)
        bFr[o] = pack2(cvtpk(acc[o].x, acc[o].y), cvtpk(acc[o].z, acc[o].w));
}

// grid 256 = 64 b x 4 segments; ONE wave per block; no LDS, no manual waitcnt.
// B0 = E_0^T fragments (strictly positive, NO identity); steps use tiles 1..n-1.
// acc_final = E_{n-1}^T ... E_0^T. Self-check validates all fragment maps at step 1.
__launch_bounds__(64, 1)
__global__ void seg_kernel(const float* __restrict__ scores,
                           const int* __restrict__ lengths,
                           float* __restrict__ wsW,
                           int* __restrict__ flags) {
    const int bid  = blockIdx.x;
    const int b    = bid >> 2;
    const int seg  = bid & 3;
    const int lane = threadIdx.x;

    int len = lengths[b]; len = min(max(len, 1), T_);
    const int last_t  = len - 1;
    const int segbase = seg * 64;
    const int cap     = (seg == 3) ? 63 : 64;
    const int n       = min(max(last_t - segbase, 0), cap);

    float* Wp = wsW + (size_t)bid * KK;

    if (n == 0) {   // identity transfer in log2 domain
        for (int e = lane; e < KK; e += 64) {
            int m = e / K_, c = e - m * K_;
            Wp[e] = (m == c) ? 0.f : NEGBIG;
        }
        if (lane == 0) flags[bid] = 0;
        return;
    }
    if (n <= 2) {   // too short for checked MFMA path: exact fallback in combine
        if (lane == 0) flags[bid] = 3;
        return;
    }

    const float* sb  = scores + (size_t)b * T_ * KK;
    const float* tb  = sb + (size_t)(segbase + 1) * KK;   // tile k <-> t = segbase+1+k
    const float* tg0 = tb;
    const float* tg1 = tb + KK;

    const int col = lane & 15, L = lane >> 4;

    // ---- B0 = E_0^T fragments: B[16kc+4L+j][16ct+col] = EX(tg0[(16ct+col)*48 + 16kc+4L+j])
    s16x4 aFr[9], bFr[9];
    f32x4 acc[9];
#pragma unroll
    for (int kc = 0; kc < 3; ++kc)
#pragma unroll
        for (int ct = 0; ct < 3; ++ct) {
            const float4 q = *(const float4*)(tg0 + (16 * ct + col) * K_ + 16 * kc + 4 * L);
            bFr[kc * 3 + ct] = pack2(cvtpk(EX(q.x), EX(q.y)), cvtpk(EX(q.z), EX(q.w)));
        }

    const int nt = n - 1;           // MFMA steps, over tiles 1..n-1 (nt >= 2 here)
    float rawA[36], rawB[36];
    load_tile(rawA, tb, 1, L, col);
    load_tile(rawB, tb, 2, L, col);

    bool chkbad = false;
    int i = 0;
#pragma unroll 1
    while (i + 1 < nt) {
        conv_step(rawA, aFr);
        if (i + 3 <= nt) load_tile(rawA, tb, i + 3, L, col);   // tile (1+i)+2
        mm_step(aFr, bFr, acc);
        if (i == 0) {
            // ---- self-check: 2 acc entries vs from-global f32 reference ----
            const int row0 = 4 * L,          c0 = col;        // (rt,ct,r)=(0,0,0)
            const int row1 = 32 + 4 * L + 3, c1 = 16 + col;   // (rt,ct,r)=(2,1,3)
            float ref0 = 0.f, ref1 = 0.f;
#pragma unroll 4
            for (int k = 0; k < K_; ++k) {
                ref0 += bfr(EX(tg1[k * K_ + row0])) * bfr(EX(tg0[c0 * K_ + k]));
                ref1 += bfr(EX(tg1[k * K_ + row1])) * bfr(EX(tg0[c1 * K_ + k]));
            }
            const float a0 = acc[0][0], a1 = acc[2 * 3 + 1][3];
            chkbad = (fabsf(ref0 - a0) > 0.03f * fmaxf(fabsf(ref0), 1e-20f)) ||
                     (fabsf(ref1 - a1) > 0.03f * fmaxf(fabsf(ref1), 1e-20f));
        }
        conv_step(rawB, aFr);
        if (i + 4 <= nt) load_tile(rawB, tb, i + 4, L, col);   // tile (2+i)+2
        mm_step(aFr, bFr, acc);
        i += 2;
    }
    if (i < nt) {         // odd nt tail: last tile lives in rawA
        conv_step(rawA, aFr);
        mm_step(aFr, bFr, acc);
    }

    // ---- epilogue: range flag + W = clamp(log2(acc)) + 6n ----
    const float sh = ESHIFT * (float)n;
    bool rbad = false;
#pragma unroll
    for (int rt = 0; rt < 3; ++rt)
#pragma unroll
        for (int ct = 0; ct < 3; ++ct)
#pragma unroll
            for (int r = 0; r < 4; ++r) {
                const float x = acc[rt * 3 + ct][r];
                rbad = rbad || !(x > 0.f && x < 3.0e38f);
                const float w = fminf(fmaxf(LOG2F(x), NEGBIG), POSBIG);
                Wp[(rt * 16 + 4 * L + r) * K_ + ct * 16 + col] = w + sh;
            }
    const bool anybad = __any(chkbad) ? true : (__any(rbad) ? true : false);
    if (lane == 0) flags[bid] = __any(chkbad) ? 2 : (__any(rbad) ? 1 : 0);
    (void)anybad;
}

// grid 64 (one per b), block 64: compose init with 4 segment matrices + gold.
// Flagged segments are recomputed exactly (scalar LSE per step, proven in R9/R10).
__global__ void combine_kernel(const float* __restrict__ scores,
                               const int* __restrict__ targets,
                               const int* __restrict__ lengths,
                               const float* __restrict__ wsW,
                               const int* __restrict__ flags,
                               float* __restrict__ losses) {
    __shared__ float vsh[K_];
    __shared__ __align__(16) float tile[KK];
    const int b = blockIdx.x;
    const int j = threadIdx.x;
    int len = lengths[b]; len = min(max(len, 1), T_);
    const int last_t = len - 1;
    const float* sb = scores + (size_t)b * T_ * KK;

    float g = 0.f;
#pragma unroll
    for (int r = 0; r < 4; ++r) {
        int t = j + 64 * r;
        if (t < len) g += sb[(size_t)t * KK + targets[b * T_ + t]];
    }
#pragma unroll
    for (int off = 1; off < 64; off <<= 1) g += __shfl_xor(g, off);

    float v = (j < K_) ? sb[START_TAG * K_ + j] * LOG2E : 0.f;   // log2 units

#pragma unroll 1
    for (int s = 0; s < 4; ++s) {
        const int cap = (s == 3) ? 63 : 64;
        const int ns  = min(max(last_t - 64 * s, 0), cap);
        if (ns == 0) continue;
        const int flag = flags[b * 4 + s];

        __syncthreads();
        if (j < K_) vsh[j] = v;
        __syncthreads();

        if (!flag) {
            if (j < K_) {
                const float* Wr = wsW + (size_t)(b * 4 + s) * KK + j * K_;
                float m = -3.0e38f;
                float xs[K_];
#pragma unroll
                for (int c = 0; c < K_; ++c) { xs[c] = vsh[c] + Wr[c]; m = fmaxf(m, xs[c]); }
                float ssum = 0.f;
#pragma unroll
                for (int c = 0; c < K_; ++c) ssum += EXP2F(xs[c] - m);
                v = m + LOG2F(ssum);
            }
        } else {
            // exact scalar recompute of this segment's steps
#pragma unroll 1
            for (int k = 0; k < ns; ++k) {
                const float* st = sb + (size_t)(64 * s + 1 + k) * KK;
                for (int q = j; q < KK / 4; q += 64)
                    ((float4*)tile)[q] = ((const float4*)st)[q];
                __syncthreads();
                float vn = 0.f;
                if (j < K_) {
                    float m = -3.0e38f;
#pragma unroll
                    for (int i2 = 0; i2 < K_; ++i2)
                        m = fmaxf(m, vsh[i2] + tile[i2 * K_ + j] * LOG2E);
                    float ssum = 0.f;
#pragma unroll
                    for (int i2 = 0; i2 < K_; ++i2)
                        ssum += EXP2F(vsh[i2] + tile[i2 * K_ + j] * LOG2E - m);
                    vn = m + LOG2F(ssum);
                }
                __syncthreads();
                if (j < K_) vsh[j] = vn;
                __syncthreads();
            }
            if (j < K_) v = vsh[j];
        }
    }

    float vEnd = __shfl(v, END_TAG);
    if (j == 0) losses[b] = LN2 * vEnd - g;
}

__global__ void reduce_kernel(const float* __restrict__ losses, float* __restrict__ out) {
    float v = losses[threadIdx.x];
#pragma unroll
    for (int off = 1; off < 64; off <<= 1) v += __shfl_xor(v, off);
    if (threadIdx.x == 0) out[0] = v * (1.0f / 64.0f);
}

extern "C" void kernel_launch(void* const* d_in, const int* in_sizes, int n_in,
                              void* d_out, int out_size, void* d_ws, size_t ws_size,
                              hipStream_t stream) {
    const float* scores  = (const float*)d_in[0];
    const int*   targets = (const int*)d_in[1];
    const int*   lengths = (const int*)d_in[2];
    float* wsW    = (float*)d_ws;                 // 256 * 2304 floats
    float* losses = wsW + 256 * KK;               // + 64 floats
    int*   flags  = (int*)(losses + 64);          // + 256 ints

    seg_kernel<<<dim3(256), dim3(64), 0, stream>>>(scores, lengths, wsW, flags);
    combine_kernel<<<dim3(64), dim3(64), 0, stream>>>(scores, targets, lengths, wsW, flags, losses);
    reduce_kernel<<<dim3(1), dim3(64), 0, stream>>>(losses, (float*)d_out);
}